// Round 1
// baseline (2918.206 us; speedup 1.0000x reference)
//
#include <hip/hip_runtime.h>
#include <hip/hip_bf16.h>

// ---------------- helpers ----------------

__device__ __forceinline__ unsigned fmap_order(float f) {
    unsigned u = __float_as_uint(f);
    return (u & 0x80000000u) ? ~u : (u | 0x80000000u);
}
__device__ __forceinline__ float funmap_order(unsigned u) {
    unsigned v = (u & 0x80000000u) ? (u & 0x7fffffffu) : ~u;
    return __uint_as_float(v);
}

// ---------------- GEMM: C[N,256] = A[N,K] @ B[K,256] (fp32) ----------------
// 64x64 tile, 256 threads, 4x4 per thread, K-chunk 16.
__global__ __launch_bounds__(256) void gemm64(const float* __restrict__ A,
                                              const float* __restrict__ B,
                                              float* __restrict__ C,
                                              int N, int K) {
    __shared__ float As[16][64];  // [k][row]
    __shared__ float Bs[16][64];  // [k][col]
    const int tid = threadIdx.x;
    const int rowBase = blockIdx.x * 64;
    const int colBase = blockIdx.y * 64;
    const int ty = tid >> 4;       // 0..15 (row group)
    const int tx = tid & 15;       // 0..15 (col group)

    const int a_row = tid >> 2;        // 0..63
    const int a_k4  = (tid & 3) * 4;   // 0,4,8,12
    const int b_k   = tid >> 4;        // 0..15
    const int b_c4  = (tid & 15) * 4;  // 0..60

    float acc[4][4];
#pragma unroll
    for (int i = 0; i < 4; ++i)
#pragma unroll
        for (int j = 0; j < 4; ++j) acc[i][j] = 0.f;

    for (int kc = 0; kc < K; kc += 16) {
        int grow = rowBase + a_row;
        float4 av = make_float4(0.f, 0.f, 0.f, 0.f);
        if (grow < N) av = *(const float4*)(A + (size_t)grow * K + kc + a_k4);
        As[a_k4 + 0][a_row] = av.x;
        As[a_k4 + 1][a_row] = av.y;
        As[a_k4 + 2][a_row] = av.z;
        As[a_k4 + 3][a_row] = av.w;
        float4 bv = *(const float4*)(B + (size_t)(kc + b_k) * 256 + colBase + b_c4);
        *(float4*)&Bs[b_k][b_c4] = bv;
        __syncthreads();
#pragma unroll
        for (int k = 0; k < 16; ++k) {
            float a0 = As[k][ty * 4 + 0], a1 = As[k][ty * 4 + 1];
            float a2 = As[k][ty * 4 + 2], a3 = As[k][ty * 4 + 3];
            float b0 = Bs[k][tx * 4 + 0], b1 = Bs[k][tx * 4 + 1];
            float b2 = Bs[k][tx * 4 + 2], b3 = Bs[k][tx * 4 + 3];
            acc[0][0] += a0 * b0; acc[0][1] += a0 * b1; acc[0][2] += a0 * b2; acc[0][3] += a0 * b3;
            acc[1][0] += a1 * b0; acc[1][1] += a1 * b1; acc[1][2] += a1 * b2; acc[1][3] += a1 * b3;
            acc[2][0] += a2 * b0; acc[2][1] += a2 * b1; acc[2][2] += a2 * b2; acc[2][3] += a2 * b3;
            acc[3][0] += a3 * b0; acc[3][1] += a3 * b1; acc[3][2] += a3 * b2; acc[3][3] += a3 * b3;
        }
        __syncthreads();
    }
#pragma unroll
    for (int i = 0; i < 4; ++i) {
        int r = rowBase + ty * 4 + i;
        if (r < N) {
            float4 v = make_float4(acc[i][0], acc[i][1], acc[i][2], acc[i][3]);
            *(float4*)(C + (size_t)r * 256 + colBase + tx * 4) = v;
        }
    }
}

// ---------------- alpha: per node dot(h, a_src), dot(h, a_dst) ----------------
__global__ __launch_bounds__(256) void alpha_kernel(const float* __restrict__ h,
                                                    const float* __restrict__ a_src,
                                                    const float* __restrict__ a_dst,
                                                    float* __restrict__ as_out,
                                                    float* __restrict__ ad_out, int N) {
    int wave = threadIdx.x >> 6;
    int lane = threadIdx.x & 63;
    int n = blockIdx.x * 4 + wave;
    if (n >= N) return;
    const float* hr = h + (size_t)n * 256;
    float s1 = 0.f, s2 = 0.f;
#pragma unroll
    for (int c = lane; c < 256; c += 64) {
        float v = hr[c];
        s1 += v * a_src[c];
        s2 += v * a_dst[c];
    }
#pragma unroll
    for (int off = 32; off > 0; off >>= 1) {
        s1 += __shfl_down(s1, off, 64);
        s2 += __shfl_down(s2, off, 64);
    }
    if (lane == 0) {
        as_out[n] = s1;
        ad_out[n] = s2;
    }
}

// ---------------- edge pass 1: e = leaky_relu(as[src]+ad[dst]); segment max ----------------
__global__ __launch_bounds__(256) void edge_e_kernel(const float* __restrict__ asrc,
                                                     const float* __restrict__ adst,
                                                     const int* __restrict__ esrc,
                                                     const int* __restrict__ edst,
                                                     int E, int N,
                                                     float* __restrict__ e_buf,
                                                     unsigned* __restrict__ m_u) {
    int i = blockIdx.x * 256 + threadIdx.x;
    int EE = E + N;
    if (i >= EE) return;
    int s, d;
    if (i < E) { s = esrc[i]; d = edst[i]; } else { s = i - E; d = s; }
    float v = asrc[s] + adst[d];
    float e = v >= 0.f ? v : 0.2f * v;
    e_buf[i] = e;
    atomicMax(&m_u[d], fmap_order(e));
}

__global__ __launch_bounds__(256) void mconv_kernel(const unsigned* __restrict__ m_u,
                                                    float* __restrict__ m_f, int N) {
    int n = blockIdx.x * 256 + threadIdx.x;
    if (n < N) m_f[n] = funmap_order(m_u[n]);
}

// ---------------- edge pass 2: p = exp(e - m[dst]); segment sum ----------------
__global__ __launch_bounds__(256) void edge_p_kernel(const float* __restrict__ m_f,
                                                     const int* __restrict__ edst,
                                                     int E, int N,
                                                     float* __restrict__ e_buf,
                                                     float* __restrict__ ssum) {
    int i = blockIdx.x * 256 + threadIdx.x;
    int EE = E + N;
    if (i >= EE) return;
    int d = (i < E) ? edst[i] : (i - E);
    float p = expf(e_buf[i] - m_f[d]);
    e_buf[i] = p;
    atomicAdd(&ssum[d], p);
}

// ---------------- edge pass 3: out[dst] += (p/s[dst]) * h[src] ----------------
__global__ __launch_bounds__(256) void aggregate_kernel(const float* __restrict__ h,
                                                        const float* __restrict__ p_buf,
                                                        const float* __restrict__ ssum,
                                                        const int* __restrict__ esrc,
                                                        const int* __restrict__ edst,
                                                        int E, int N,
                                                        float* __restrict__ out) {
    int i = blockIdx.x;
    int s, d;
    if (i < E) { s = esrc[i]; d = edst[i]; } else { s = i - E; d = s; }
    float coef = p_buf[i] / ssum[d];
    int c = threadIdx.x;
    atomicAdd(&out[(size_t)d * 256 + c], coef * h[(size_t)s * 256 + c]);
}

// ---------------- bias + relu (in place) ----------------
__global__ __launch_bounds__(256) void bias_relu_kernel(float* __restrict__ h,
                                                        const float* __restrict__ b,
                                                        int total) {
    int idx = blockIdx.x * 256 + threadIdx.x;
    if (idx < total) {
        h[idx] = fmaxf(h[idx] + b[idx & 255], 0.f);
    }
}

// ---------------- mean pool ----------------
__global__ __launch_bounds__(256) void pool_kernel(const float* __restrict__ h,
                                                   const int* __restrict__ batch,
                                                   float* __restrict__ gsum,
                                                   float* __restrict__ gcnt, int N) {
    int n = blockIdx.x;
    int c = threadIdx.x;
    int g = batch[n];
    atomicAdd(&gsum[(size_t)g * 256 + c], h[(size_t)n * 256 + c]);
    if (c == 0) atomicAdd(&gcnt[g], 1.0f);
}

// ---------------- final: pooled@Wfc + bfc, softmax ----------------
__global__ __launch_bounds__(256) void final_kernel(const float* __restrict__ gsum,
                                                    const float* __restrict__ gcnt,
                                                    const float* __restrict__ Wfc,
                                                    const float* __restrict__ bfc,
                                                    float* __restrict__ out) {
    __shared__ float red0[256];
    __shared__ float red1[256];
    int g = blockIdx.x;
    int c = threadIdx.x;
    float inv = 1.0f / fmaxf(gcnt[g], 1.0f);
    float v = gsum[(size_t)g * 256 + c] * inv;
    red0[c] = v * Wfc[c * 2 + 0];
    red1[c] = v * Wfc[c * 2 + 1];
    __syncthreads();
    for (int off = 128; off > 0; off >>= 1) {
        if (c < off) {
            red0[c] += red0[c + off];
            red1[c] += red1[c + off];
        }
        __syncthreads();
    }
    if (c == 0) {
        float l0 = red0[0] + bfc[0];
        float l1 = red1[0] + bfc[1];
        float mx = fmaxf(l0, l1);
        float e0 = expf(l0 - mx), e1 = expf(l1 - mx);
        float s = e0 + e1;
        out[g * 2 + 0] = e0 / s;
        out[g * 2 + 1] = e1 / s;
    }
}

// ---------------- launch ----------------
extern "C" void kernel_launch(void* const* d_in, const int* in_sizes, int n_in,
                              void* d_out, int out_size, void* d_ws, size_t ws_size,
                              hipStream_t stream) {
    const float* x    = (const float*)d_in[0];
    const int*   eidx = (const int*)d_in[1];
    const int*   batch= (const int*)d_in[2];
    const float* Wl[3]  = {(const float*)d_in[3], (const float*)d_in[7],  (const float*)d_in[11]};
    const float* asl[3] = {(const float*)d_in[4], (const float*)d_in[8],  (const float*)d_in[12]};
    const float* adl[3] = {(const float*)d_in[5], (const float*)d_in[9],  (const float*)d_in[13]};
    const float* bl[3]  = {(const float*)d_in[6], (const float*)d_in[10], (const float*)d_in[14]};
    const float* Wfc = (const float*)d_in[15];
    const float* bfc = (const float*)d_in[16];
    float* out = (float*)d_out;

    const int N  = in_sizes[2];
    const int E  = in_sizes[1] / 2;
    const int EE = E + N;
    const int DH = 256;
    const int G  = 512;
    const int* esrc = eidx;
    const int* edst = eidx + E;

    char* ws = (char*)d_ws;
    size_t off = 0;
    const size_t featBytes = (size_t)N * DH * sizeof(float);
    float*    bufA  = (float*)(ws + off); off += featBytes;   // h (transformed)
    float*    bufB  = (float*)(ws + off); off += featBytes;   // layer io / accumulator
    float*    asrc  = (float*)(ws + off); off += (size_t)N * sizeof(float);
    float*    adst  = (float*)(ws + off); off += (size_t)N * sizeof(float);
    unsigned* m_u   = (unsigned*)(ws + off); off += (size_t)N * sizeof(unsigned);
    float*    m_f   = (float*)(ws + off); off += (size_t)N * sizeof(float);
    float*    ssum  = (float*)(ws + off); off += (size_t)N * sizeof(float);
    float*    e_buf = (float*)(ws + off); off += (size_t)EE * sizeof(float);
    float*    gsum  = (float*)(ws + off); off += (size_t)G * DH * sizeof(float);
    float*    gcnt  = (float*)(ws + off); off += (size_t)G * sizeof(float);

    for (int layer = 0; layer < 3; ++layer) {
        const float* in = (layer == 0) ? x : bufB;
        const int K = (layer == 0) ? 128 : 256;

        dim3 ggrid((N + 63) / 64, 4);
        gemm64<<<ggrid, 256, 0, stream>>>(in, Wl[layer], bufA, N, K);

        alpha_kernel<<<(N + 3) / 4, 256, 0, stream>>>(bufA, asl[layer], adl[layer], asrc, adst, N);

        hipMemsetAsync(m_u, 0, (size_t)N * sizeof(unsigned), stream);
        hipMemsetAsync(ssum, 0, (size_t)N * sizeof(float), stream);

        edge_e_kernel<<<(EE + 255) / 256, 256, 0, stream>>>(asrc, adst, esrc, edst, E, N, e_buf, m_u);
        mconv_kernel<<<(N + 255) / 256, 256, 0, stream>>>(m_u, m_f, N);
        edge_p_kernel<<<(EE + 255) / 256, 256, 0, stream>>>(m_f, edst, E, N, e_buf, ssum);

        hipMemsetAsync(bufB, 0, featBytes, stream);
        aggregate_kernel<<<EE, 256, 0, stream>>>(bufA, e_buf, ssum, esrc, edst, E, N, bufB);

        bias_relu_kernel<<<((size_t)N * DH + 255) / 256, 256, 0, stream>>>(bufB, bl[layer], N * DH);
    }

    hipMemsetAsync(gsum, 0, (size_t)G * DH * sizeof(float), stream);
    hipMemsetAsync(gcnt, 0, (size_t)G * sizeof(float), stream);
    pool_kernel<<<N, 256, 0, stream>>>(bufB, batch, gsum, gcnt, N);
    final_kernel<<<G, 256, 0, stream>>>(gsum, gcnt, Wfc, bfc, out);
}

// Round 2
// 952.244 us; speedup vs baseline: 3.0646x; 3.0646x over previous
//
#include <hip/hip_runtime.h>
#include <hip/hip_bf16.h>

// ---------------- GEMM: C[N,256] = A[N,K] @ B[K,256] (fp32) ----------------
// 64x64 tile, 256 threads, 4x4 per thread, K-chunk 16.
__global__ __launch_bounds__(256) void gemm64(const float* __restrict__ A,
                                              const float* __restrict__ B,
                                              float* __restrict__ C,
                                              int N, int K) {
    __shared__ float As[16][64];  // [k][row]
    __shared__ float Bs[16][64];  // [k][col]
    const int tid = threadIdx.x;
    const int rowBase = blockIdx.x * 64;
    const int colBase = blockIdx.y * 64;
    const int ty = tid >> 4;       // 0..15 (row group)
    const int tx = tid & 15;       // 0..15 (col group)

    const int a_row = tid >> 2;        // 0..63
    const int a_k4  = (tid & 3) * 4;   // 0,4,8,12
    const int b_k   = tid >> 4;        // 0..15
    const int b_c4  = (tid & 15) * 4;  // 0..60

    float acc[4][4];
#pragma unroll
    for (int i = 0; i < 4; ++i)
#pragma unroll
        for (int j = 0; j < 4; ++j) acc[i][j] = 0.f;

    for (int kc = 0; kc < K; kc += 16) {
        int grow = rowBase + a_row;
        float4 av = make_float4(0.f, 0.f, 0.f, 0.f);
        if (grow < N) av = *(const float4*)(A + (size_t)grow * K + kc + a_k4);
        As[a_k4 + 0][a_row] = av.x;
        As[a_k4 + 1][a_row] = av.y;
        As[a_k4 + 2][a_row] = av.z;
        As[a_k4 + 3][a_row] = av.w;
        float4 bv = *(const float4*)(B + (size_t)(kc + b_k) * 256 + colBase + b_c4);
        *(float4*)&Bs[b_k][b_c4] = bv;
        __syncthreads();
#pragma unroll
        for (int k = 0; k < 16; ++k) {
            float a0 = As[k][ty * 4 + 0], a1 = As[k][ty * 4 + 1];
            float a2 = As[k][ty * 4 + 2], a3 = As[k][ty * 4 + 3];
            float b0 = Bs[k][tx * 4 + 0], b1 = Bs[k][tx * 4 + 1];
            float b2 = Bs[k][tx * 4 + 2], b3 = Bs[k][tx * 4 + 3];
            acc[0][0] += a0 * b0; acc[0][1] += a0 * b1; acc[0][2] += a0 * b2; acc[0][3] += a0 * b3;
            acc[1][0] += a1 * b0; acc[1][1] += a1 * b1; acc[1][2] += a1 * b2; acc[1][3] += a1 * b3;
            acc[2][0] += a2 * b0; acc[2][1] += a2 * b1; acc[2][2] += a2 * b2; acc[2][3] += a2 * b3;
            acc[3][0] += a3 * b0; acc[3][1] += a3 * b1; acc[3][2] += a3 * b2; acc[3][3] += a3 * b3;
        }
        __syncthreads();
    }
#pragma unroll
    for (int i = 0; i < 4; ++i) {
        int r = rowBase + ty * 4 + i;
        if (r < N) {
            float4 v = make_float4(acc[i][0], acc[i][1], acc[i][2], acc[i][3]);
            *(float4*)(C + (size_t)r * 256 + colBase + tx * 4) = v;
        }
    }
}

// ---------------- alpha: per node dot(h, a_src), dot(h, a_dst) ----------------
__global__ __launch_bounds__(256) void alpha_kernel(const float* __restrict__ h,
                                                    const float* __restrict__ a_src,
                                                    const float* __restrict__ a_dst,
                                                    float* __restrict__ as_out,
                                                    float* __restrict__ ad_out, int N) {
    int wave = threadIdx.x >> 6;
    int lane = threadIdx.x & 63;
    int n = blockIdx.x * 4 + wave;
    if (n >= N) return;
    const float* hr = h + (size_t)n * 256;
    float s1 = 0.f, s2 = 0.f;
#pragma unroll
    for (int c = lane; c < 256; c += 64) {
        float v = hr[c];
        s1 += v * a_src[c];
        s2 += v * a_dst[c];
    }
#pragma unroll
    for (int off = 32; off > 0; off >>= 1) {
        s1 += __shfl_down(s1, off, 64);
        s2 += __shfl_down(s2, off, 64);
    }
    if (lane == 0) {
        as_out[n] = s1;
        ad_out[n] = s2;
    }
}

// ---------------- CSR build ----------------
__global__ __launch_bounds__(256) void count_kernel(const int* __restrict__ edst,
                                                    int* __restrict__ deg, int E) {
    int i = blockIdx.x * 256 + threadIdx.x;
    if (i < E) atomicAdd(&deg[edst[i]], 1);
}

// per-block exclusive scan (256 elems), emits block sums
__global__ __launch_bounds__(256) void scan1_kernel(const int* __restrict__ deg,
                                                    int* __restrict__ excl,
                                                    int* __restrict__ bsum, int N) {
    __shared__ int tmp[256];
    int tid = threadIdx.x;
    int i = blockIdx.x * 256 + tid;
    int v = (i < N) ? deg[i] : 0;
    tmp[tid] = v;
    __syncthreads();
    for (int off = 1; off < 256; off <<= 1) {
        int t = (tid >= off) ? tmp[tid - off] : 0;
        __syncthreads();
        tmp[tid] += t;
        __syncthreads();
    }
    if (i < N) excl[i] = tmp[tid] - v;
    if (tid == 255) bsum[blockIdx.x] = tmp[255];
}

// single-block exclusive scan of block sums (nb <= 256)
__global__ __launch_bounds__(256) void scan2_kernel(int* __restrict__ bsum, int nb) {
    __shared__ int tmp[256];
    int tid = threadIdx.x;
    int v = (tid < nb) ? bsum[tid] : 0;
    tmp[tid] = v;
    __syncthreads();
    for (int off = 1; off < 256; off <<= 1) {
        int t = (tid >= off) ? tmp[tid - off] : 0;
        __syncthreads();
        tmp[tid] += t;
        __syncthreads();
    }
    if (tid < nb) bsum[tid] = tmp[tid] - v;
}

__global__ __launch_bounds__(256) void scan3_kernel(const int* __restrict__ excl,
                                                    const int* __restrict__ bsum,
                                                    int* __restrict__ rowptr,
                                                    int* __restrict__ cursor,
                                                    int N, int E) {
    int i = blockIdx.x * 256 + threadIdx.x;
    if (i < N) {
        int v = excl[i] + bsum[blockIdx.x];
        rowptr[i] = v;
        cursor[i] = v;
    }
    if (i == 0) rowptr[N] = E;
}

__global__ __launch_bounds__(256) void scatter_kernel(const int* __restrict__ esrc,
                                                      const int* __restrict__ edst,
                                                      int* __restrict__ cursor,
                                                      int* __restrict__ csr_src, int E) {
    int i = blockIdx.x * 256 + threadIdx.x;
    if (i < E) {
        int d = edst[i];
        int pos = atomicAdd(&cursor[d], 1);
        csr_src[pos] = esrc[i];
    }
}

// ---------------- fused GAT aggregation: one wave per dst node ----------------
// online softmax over in-edges + self loop; gather h[src]; bias + relu fused.
__global__ __launch_bounds__(256) void gat_fused_kernel(const float* __restrict__ h,
                                                        const float* __restrict__ asrc,
                                                        const float* __restrict__ adst,
                                                        const int* __restrict__ rowptr,
                                                        const int* __restrict__ csr_src,
                                                        const float* __restrict__ bias,
                                                        float* __restrict__ out, int N) {
    int wave = threadIdx.x >> 6;
    int lane = threadIdx.x & 63;
    int d = blockIdx.x * 4 + wave;
    if (d >= N) return;

    float ad = adst[d];
    // self loop first (p = exp(e_self - m) = 1 with m = e_self)
    float es = asrc[d] + ad;
    es = es >= 0.f ? es : 0.2f * es;
    float m = es;
    float s = 1.0f;
    float4 acc = *(const float4*)(h + (size_t)d * 256 + lane * 4);

    int beg = rowptr[d], end = rowptr[d + 1];
    for (int base = beg; base < end; base += 64) {
        int cnt = min(64, end - base);
        int srci = 0;
        float e = -1e30f;
        if (lane < cnt) {
            srci = csr_src[base + lane];
            float v = asrc[srci] + ad;
            e = v >= 0.f ? v : 0.2f * v;
        }
        // wave max (butterfly so all lanes hold it)
        float cm = e;
#pragma unroll
        for (int off = 32; off > 0; off >>= 1) cm = fmaxf(cm, __shfl_xor(cm, off, 64));
        float mnew = fmaxf(m, cm);
        float scale = __expf(m - mnew);
        s *= scale;
        acc.x *= scale; acc.y *= scale; acc.z *= scale; acc.w *= scale;
        m = mnew;
        for (int j = 0; j < cnt; ++j) {
            float ej = __shfl(e, j, 64);
            int sj = __shfl(srci, j, 64);
            float p = __expf(ej - m);
            float4 hv = *(const float4*)(h + (size_t)sj * 256 + lane * 4);
            s += p;
            acc.x += p * hv.x; acc.y += p * hv.y; acc.z += p * hv.z; acc.w += p * hv.w;
        }
    }
    float inv = 1.0f / s;
    float4 bv = *(const float4*)(bias + lane * 4);
    float4 o;
    o.x = fmaxf(acc.x * inv + bv.x, 0.f);
    o.y = fmaxf(acc.y * inv + bv.y, 0.f);
    o.z = fmaxf(acc.z * inv + bv.z, 0.f);
    o.w = fmaxf(acc.w * inv + bv.w, 0.f);
    *(float4*)(out + (size_t)d * 256 + lane * 4) = o;
}

// ---------------- mean pool ----------------
__global__ __launch_bounds__(256) void pool_kernel(const float* __restrict__ h,
                                                   const int* __restrict__ batch,
                                                   float* __restrict__ gsum,
                                                   float* __restrict__ gcnt, int N) {
    int n = blockIdx.x;
    int c = threadIdx.x;
    int g = batch[n];
    atomicAdd(&gsum[(size_t)g * 256 + c], h[(size_t)n * 256 + c]);
    if (c == 0) atomicAdd(&gcnt[g], 1.0f);
}

// ---------------- final: pooled@Wfc + bfc, softmax ----------------
__global__ __launch_bounds__(256) void final_kernel(const float* __restrict__ gsum,
                                                    const float* __restrict__ gcnt,
                                                    const float* __restrict__ Wfc,
                                                    const float* __restrict__ bfc,
                                                    float* __restrict__ out) {
    __shared__ float red0[256];
    __shared__ float red1[256];
    int g = blockIdx.x;
    int c = threadIdx.x;
    float inv = 1.0f / fmaxf(gcnt[g], 1.0f);
    float v = gsum[(size_t)g * 256 + c] * inv;
    red0[c] = v * Wfc[c * 2 + 0];
    red1[c] = v * Wfc[c * 2 + 1];
    __syncthreads();
    for (int off = 128; off > 0; off >>= 1) {
        if (c < off) {
            red0[c] += red0[c + off];
            red1[c] += red1[c + off];
        }
        __syncthreads();
    }
    if (c == 0) {
        float l0 = red0[0] + bfc[0];
        float l1 = red1[0] + bfc[1];
        float mx = fmaxf(l0, l1);
        float e0 = expf(l0 - mx), e1 = expf(l1 - mx);
        float s = e0 + e1;
        out[g * 2 + 0] = e0 / s;
        out[g * 2 + 1] = e1 / s;
    }
}

// ---------------- launch ----------------
extern "C" void kernel_launch(void* const* d_in, const int* in_sizes, int n_in,
                              void* d_out, int out_size, void* d_ws, size_t ws_size,
                              hipStream_t stream) {
    const float* x    = (const float*)d_in[0];
    const int*   eidx = (const int*)d_in[1];
    const int*   batch= (const int*)d_in[2];
    const float* Wl[3]  = {(const float*)d_in[3], (const float*)d_in[7],  (const float*)d_in[11]};
    const float* asl[3] = {(const float*)d_in[4], (const float*)d_in[8],  (const float*)d_in[12]};
    const float* adl[3] = {(const float*)d_in[5], (const float*)d_in[9],  (const float*)d_in[13]};
    const float* bl[3]  = {(const float*)d_in[6], (const float*)d_in[10], (const float*)d_in[14]};
    const float* Wfc = (const float*)d_in[15];
    const float* bfc = (const float*)d_in[16];
    float* out = (float*)d_out;

    const int N  = in_sizes[2];
    const int E  = in_sizes[1] / 2;
    const int DH = 256;
    const int G  = 512;
    const int* esrc = eidx;
    const int* edst = eidx + E;

    char* ws = (char*)d_ws;
    size_t off = 0;
    const size_t featBytes = (size_t)N * DH * sizeof(float);
    float* bufA   = (float*)(ws + off); off += featBytes;   // h (transformed)
    float* bufB   = (float*)(ws + off); off += featBytes;   // layer output
    float* asrc   = (float*)(ws + off); off += (size_t)N * sizeof(float);
    float* adst   = (float*)(ws + off); off += (size_t)N * sizeof(float);
    int*   deg    = (int*)(ws + off);   off += (size_t)N * sizeof(int);
    int*   excl   = (int*)(ws + off);   off += (size_t)N * sizeof(int);
    int*   rowptr = (int*)(ws + off);   off += (size_t)(N + 1) * sizeof(int);
    int*   cursor = (int*)(ws + off);   off += (size_t)N * sizeof(int);
    int*   bsum   = (int*)(ws + off);   off += 1024;
    int*   csrsrc = (int*)(ws + off);   off += (size_t)E * sizeof(int);
    float* gsum   = (float*)(ws + off); off += (size_t)G * DH * sizeof(float);
    float* gcnt   = (float*)(ws + off); off += (size_t)G * sizeof(float);

    const int nbN = (N + 255) / 256;

    // ---- build CSR by dst (graph-independent of layers; once per launch) ----
    hipMemsetAsync(deg, 0, (size_t)N * sizeof(int), stream);
    count_kernel<<<(E + 255) / 256, 256, 0, stream>>>(edst, deg, E);
    scan1_kernel<<<nbN, 256, 0, stream>>>(deg, excl, bsum, N);
    scan2_kernel<<<1, 256, 0, stream>>>(bsum, nbN);
    scan3_kernel<<<nbN, 256, 0, stream>>>(excl, bsum, rowptr, cursor, N, E);
    scatter_kernel<<<(E + 255) / 256, 256, 0, stream>>>(esrc, edst, cursor, csrsrc, E);

    for (int layer = 0; layer < 3; ++layer) {
        const float* in = (layer == 0) ? x : bufB;
        const int K = (layer == 0) ? 128 : 256;

        dim3 ggrid((N + 63) / 64, 4);
        gemm64<<<ggrid, 256, 0, stream>>>(in, Wl[layer], bufA, N, K);

        alpha_kernel<<<(N + 3) / 4, 256, 0, stream>>>(bufA, asl[layer], adl[layer], asrc, adst, N);

        gat_fused_kernel<<<(N + 3) / 4, 256, 0, stream>>>(bufA, asrc, adst, rowptr, csrsrc,
                                                          bl[layer], bufB, N);
    }

    hipMemsetAsync(gsum, 0, (size_t)G * DH * sizeof(float), stream);
    hipMemsetAsync(gcnt, 0, (size_t)G * sizeof(float), stream);
    pool_kernel<<<N, 256, 0, stream>>>(bufB, batch, gsum, gcnt, N);
    final_kernel<<<G, 256, 0, stream>>>(gsum, gcnt, Wfc, bfc, out);
}

// Round 3
// 842.471 us; speedup vs baseline: 3.4639x; 1.1303x over previous
//
#include <hip/hip_runtime.h>
#include <hip/hip_bf16.h>

// ---------------- GEMM: C[N,256] = A[N,K] @ B[K,256] (fp32) ----------------
// 64x64 tile, 256 threads, 4x4 per thread, K-chunk 16.
// Epilogue: partial dot(h_row, a_src/a_dst) accumulated via atomics (alpha fusion).
__global__ __launch_bounds__(256) void gemm64(const float* __restrict__ A,
                                              const float* __restrict__ B,
                                              float* __restrict__ C,
                                              const float* __restrict__ a_src,
                                              const float* __restrict__ a_dst,
                                              float* __restrict__ asrc_out,
                                              float* __restrict__ adst_out,
                                              int N, int K) {
    __shared__ float As[16][64];  // [k][row]
    __shared__ float Bs[16][64];  // [k][col]
    __shared__ float redS[64][17];
    __shared__ float redD[64][17];
    const int tid = threadIdx.x;
    const int rowBase = blockIdx.x * 64;
    const int colBase = blockIdx.y * 64;
    const int ty = tid >> 4;       // 0..15 (row group)
    const int tx = tid & 15;       // 0..15 (col group)

    const int a_row = tid >> 2;        // 0..63
    const int a_k4  = (tid & 3) * 4;   // 0,4,8,12
    const int b_k   = tid >> 4;        // 0..15
    const int b_c4  = (tid & 15) * 4;  // 0..60

    float acc[4][4];
#pragma unroll
    for (int i = 0; i < 4; ++i)
#pragma unroll
        for (int j = 0; j < 4; ++j) acc[i][j] = 0.f;

    for (int kc = 0; kc < K; kc += 16) {
        int grow = rowBase + a_row;
        float4 av = make_float4(0.f, 0.f, 0.f, 0.f);
        if (grow < N) av = *(const float4*)(A + (size_t)grow * K + kc + a_k4);
        As[a_k4 + 0][a_row] = av.x;
        As[a_k4 + 1][a_row] = av.y;
        As[a_k4 + 2][a_row] = av.z;
        As[a_k4 + 3][a_row] = av.w;
        float4 bv = *(const float4*)(B + (size_t)(kc + b_k) * 256 + colBase + b_c4);
        *(float4*)&Bs[b_k][b_c4] = bv;
        __syncthreads();
#pragma unroll
        for (int k = 0; k < 16; ++k) {
            float a0 = As[k][ty * 4 + 0], a1 = As[k][ty * 4 + 1];
            float a2 = As[k][ty * 4 + 2], a3 = As[k][ty * 4 + 3];
            float b0 = Bs[k][tx * 4 + 0], b1 = Bs[k][tx * 4 + 1];
            float b2 = Bs[k][tx * 4 + 2], b3 = Bs[k][tx * 4 + 3];
            acc[0][0] += a0 * b0; acc[0][1] += a0 * b1; acc[0][2] += a0 * b2; acc[0][3] += a0 * b3;
            acc[1][0] += a1 * b0; acc[1][1] += a1 * b1; acc[1][2] += a1 * b2; acc[1][3] += a1 * b3;
            acc[2][0] += a2 * b0; acc[2][1] += a2 * b1; acc[2][2] += a2 * b2; acc[2][3] += a2 * b3;
            acc[3][0] += a3 * b0; acc[3][1] += a3 * b1; acc[3][2] += a3 * b2; acc[3][3] += a3 * b3;
        }
        __syncthreads();
    }

    // load attention vector slices for this col block
    float asv[4], adv[4];
#pragma unroll
    for (int j = 0; j < 4; ++j) {
        asv[j] = a_src[colBase + tx * 4 + j];
        adv[j] = a_dst[colBase + tx * 4 + j];
    }

#pragma unroll
    for (int i = 0; i < 4; ++i) {
        int r = rowBase + ty * 4 + i;
        float s1 = acc[i][0] * asv[0] + acc[i][1] * asv[1] + acc[i][2] * asv[2] + acc[i][3] * asv[3];
        float s2 = acc[i][0] * adv[0] + acc[i][1] * adv[1] + acc[i][2] * adv[2] + acc[i][3] * adv[3];
        redS[ty * 4 + i][tx] = s1;
        redD[ty * 4 + i][tx] = s2;
        if (r < N) {
            float4 v = make_float4(acc[i][0], acc[i][1], acc[i][2], acc[i][3]);
            *(float4*)(C + (size_t)r * 256 + colBase + tx * 4) = v;
        }
    }
    __syncthreads();
    if (tid < 64) {
        int r = rowBase + tid;
        if (r < N) {
            float s1 = 0.f, s2 = 0.f;
#pragma unroll
            for (int t = 0; t < 16; ++t) { s1 += redS[tid][t]; s2 += redD[tid][t]; }
            atomicAdd(&asrc_out[r], s1);
            atomicAdd(&adst_out[r], s2);
        }
    }
}

// ---------------- CSR build ----------------
__global__ __launch_bounds__(256) void count_kernel(const int* __restrict__ edst,
                                                    int* __restrict__ deg, int E) {
    int i = blockIdx.x * 256 + threadIdx.x;
    if (i < E) atomicAdd(&deg[edst[i]], 1);
}

// per-block exclusive scan (256 elems), emits block sums
__global__ __launch_bounds__(256) void scan1_kernel(const int* __restrict__ deg,
                                                    int* __restrict__ excl,
                                                    int* __restrict__ bsum, int N) {
    __shared__ int tmp[256];
    int tid = threadIdx.x;
    int i = blockIdx.x * 256 + tid;
    int v = (i < N) ? deg[i] : 0;
    tmp[tid] = v;
    __syncthreads();
    for (int off = 1; off < 256; off <<= 1) {
        int t = (tid >= off) ? tmp[tid - off] : 0;
        __syncthreads();
        tmp[tid] += t;
        __syncthreads();
    }
    if (i < N) excl[i] = tmp[tid] - v;
    if (tid == 255) bsum[blockIdx.x] = tmp[255];
}

// single-block exclusive scan of block sums (nb <= 256)
__global__ __launch_bounds__(256) void scan2_kernel(int* __restrict__ bsum, int nb) {
    __shared__ int tmp[256];
    int tid = threadIdx.x;
    int v = (tid < nb) ? bsum[tid] : 0;
    tmp[tid] = v;
    __syncthreads();
    for (int off = 1; off < 256; off <<= 1) {
        int t = (tid >= off) ? tmp[tid - off] : 0;
        __syncthreads();
        tmp[tid] += t;
        __syncthreads();
    }
    if (tid < nb) bsum[tid] = tmp[tid] - v;
}

__global__ __launch_bounds__(256) void scan3_kernel(const int* __restrict__ excl,
                                                    const int* __restrict__ bsum,
                                                    int* __restrict__ rowptr,
                                                    int* __restrict__ cursor,
                                                    int N, int E) {
    int i = blockIdx.x * 256 + threadIdx.x;
    if (i < N) {
        int v = excl[i] + bsum[blockIdx.x];
        rowptr[i] = v;
        cursor[i] = v;
    }
    if (i == 0) rowptr[N] = E;
}

__global__ __launch_bounds__(256) void scatter_kernel(const int* __restrict__ esrc,
                                                      const int* __restrict__ edst,
                                                      int* __restrict__ cursor,
                                                      int* __restrict__ csr_src, int E) {
    int i = blockIdx.x * 256 + threadIdx.x;
    if (i < E) {
        int d = edst[i];
        int pos = atomicAdd(&cursor[d], 1);
        csr_src[pos] = esrc[i];
    }
}

// ---------------- fused GAT aggregation: one wave per dst node ----------------
// online softmax over in-edges + self loop; gather h[src]; bias + relu fused.
__global__ __launch_bounds__(256) void gat_fused_kernel(const float* __restrict__ h,
                                                        const float* __restrict__ asrc,
                                                        const float* __restrict__ adst,
                                                        const int* __restrict__ rowptr,
                                                        const int* __restrict__ csr_src,
                                                        const float* __restrict__ bias,
                                                        float* __restrict__ out, int N) {
    int wave = threadIdx.x >> 6;
    int lane = threadIdx.x & 63;
    int d = blockIdx.x * 4 + wave;
    if (d >= N) return;

    float ad = adst[d];
    // self loop first (p = exp(e_self - m) = 1 with m = e_self)
    float es = asrc[d] + ad;
    es = es >= 0.f ? es : 0.2f * es;
    float m = es;
    float s = 1.0f;
    float4 acc = *(const float4*)(h + (size_t)d * 256 + lane * 4);

    int beg = rowptr[d], end = rowptr[d + 1];
    for (int base = beg; base < end; base += 64) {
        int cnt = min(64, end - base);
        int srci = 0;
        float e = -1e30f;
        if (lane < cnt) {
            srci = csr_src[base + lane];
            float v = asrc[srci] + ad;
            e = v >= 0.f ? v : 0.2f * v;
        }
        // wave max (butterfly so all lanes hold it)
        float cm = e;
#pragma unroll
        for (int off = 32; off > 0; off >>= 1) cm = fmaxf(cm, __shfl_xor(cm, off, 64));
        float mnew = fmaxf(m, cm);
        float scale = __expf(m - mnew);
        s *= scale;
        acc.x *= scale; acc.y *= scale; acc.z *= scale; acc.w *= scale;
        m = mnew;
        for (int j = 0; j < cnt; ++j) {
            float ej = __shfl(e, j, 64);
            int sj = __shfl(srci, j, 64);
            float p = __expf(ej - m);
            float4 hv = *(const float4*)(h + (size_t)sj * 256 + lane * 4);
            s += p;
            acc.x += p * hv.x; acc.y += p * hv.y; acc.z += p * hv.z; acc.w += p * hv.w;
        }
    }
    float inv = 1.0f / s;
    float4 bv = *(const float4*)(bias + lane * 4);
    float4 o;
    o.x = fmaxf(acc.x * inv + bv.x, 0.f);
    o.y = fmaxf(acc.y * inv + bv.y, 0.f);
    o.z = fmaxf(acc.z * inv + bv.z, 0.f);
    o.w = fmaxf(acc.w * inv + bv.w, 0.f);
    *(float4*)(out + (size_t)d * 256 + lane * 4) = o;
}

// ---------------- fused mean pool + FC + softmax (batch is sorted) ----------------
__device__ __forceinline__ int lower_bound_i(const int* __restrict__ a, int n, int v) {
    int lo = 0, hi = n;
    while (lo < hi) {
        int mid = (lo + hi) >> 1;
        if (a[mid] < v) lo = mid + 1; else hi = mid;
    }
    return lo;
}

__global__ __launch_bounds__(256) void pool_fc_kernel(const float* __restrict__ h,
                                                      const int* __restrict__ batch,
                                                      int N,
                                                      const float* __restrict__ Wfc,
                                                      const float* __restrict__ bfc,
                                                      float* __restrict__ out) {
    __shared__ float red0[256];
    __shared__ float red1[256];
    int g = blockIdx.x;
    int c = threadIdx.x;
    int beg = lower_bound_i(batch, N, g);
    int end = lower_bound_i(batch, N, g + 1);
    float sum = 0.f;
    for (int n = beg; n < end; ++n) sum += h[(size_t)n * 256 + c];
    float cnt = (float)(end - beg);
    float v = sum / fmaxf(cnt, 1.0f);
    red0[c] = v * Wfc[c * 2 + 0];
    red1[c] = v * Wfc[c * 2 + 1];
    __syncthreads();
    for (int off = 128; off > 0; off >>= 1) {
        if (c < off) {
            red0[c] += red0[c + off];
            red1[c] += red1[c + off];
        }
        __syncthreads();
    }
    if (c == 0) {
        float l0 = red0[0] + bfc[0];
        float l1 = red1[0] + bfc[1];
        float mx = fmaxf(l0, l1);
        float e0 = expf(l0 - mx), e1 = expf(l1 - mx);
        float s = e0 + e1;
        out[g * 2 + 0] = e0 / s;
        out[g * 2 + 1] = e1 / s;
    }
}

// ---------------- launch ----------------
extern "C" void kernel_launch(void* const* d_in, const int* in_sizes, int n_in,
                              void* d_out, int out_size, void* d_ws, size_t ws_size,
                              hipStream_t stream) {
    const float* x    = (const float*)d_in[0];
    const int*   eidx = (const int*)d_in[1];
    const int*   batch= (const int*)d_in[2];
    const float* Wl[3]  = {(const float*)d_in[3], (const float*)d_in[7],  (const float*)d_in[11]};
    const float* asl[3] = {(const float*)d_in[4], (const float*)d_in[8],  (const float*)d_in[12]};
    const float* adl[3] = {(const float*)d_in[5], (const float*)d_in[9],  (const float*)d_in[13]};
    const float* bl[3]  = {(const float*)d_in[6], (const float*)d_in[10], (const float*)d_in[14]};
    const float* Wfc = (const float*)d_in[15];
    const float* bfc = (const float*)d_in[16];
    float* out = (float*)d_out;

    const int N  = in_sizes[2];
    const int E  = in_sizes[1] / 2;
    const int DH = 256;
    const int G  = 512;
    const int* esrc = eidx;
    const int* edst = eidx + E;

    char* ws = (char*)d_ws;
    size_t off = 0;
    const size_t featBytes = (size_t)N * DH * sizeof(float);
    float* bufA   = (float*)(ws + off); off += featBytes;   // h (transformed)
    float* bufB   = (float*)(ws + off); off += featBytes;   // layer output
    float* asrc   = (float*)(ws + off); off += (size_t)N * sizeof(float);
    float* adst   = (float*)(ws + off); off += (size_t)N * sizeof(float);
    int*   deg    = (int*)(ws + off);   off += (size_t)N * sizeof(int);
    int*   excl   = (int*)(ws + off);   off += (size_t)N * sizeof(int);
    int*   rowptr = (int*)(ws + off);   off += (size_t)(N + 1) * sizeof(int);
    int*   cursor = (int*)(ws + off);   off += (size_t)N * sizeof(int);
    int*   bsum   = (int*)(ws + off);   off += 1024;
    int*   csrsrc = (int*)(ws + off);   off += (size_t)E * sizeof(int);

    const int nbN = (N + 255) / 256;

    // ---- build CSR by dst (graph-independent of layers; once per launch) ----
    hipMemsetAsync(deg, 0, (size_t)N * sizeof(int), stream);
    count_kernel<<<(E + 255) / 256, 256, 0, stream>>>(edst, deg, E);
    scan1_kernel<<<nbN, 256, 0, stream>>>(deg, excl, bsum, N);
    scan2_kernel<<<1, 256, 0, stream>>>(bsum, nbN);
    scan3_kernel<<<nbN, 256, 0, stream>>>(excl, bsum, rowptr, cursor, N, E);
    scatter_kernel<<<(E + 255) / 256, 256, 0, stream>>>(esrc, edst, cursor, csrsrc, E);

    for (int layer = 0; layer < 3; ++layer) {
        const float* in = (layer == 0) ? x : bufB;
        const int K = (layer == 0) ? 128 : 256;

        // zero alpha accumulators (asrc,adst are adjacent)
        hipMemsetAsync(asrc, 0, 2 * (size_t)N * sizeof(float), stream);

        dim3 ggrid((N + 63) / 64, 4);
        gemm64<<<ggrid, 256, 0, stream>>>(in, Wl[layer], bufA,
                                          asl[layer], adl[layer], asrc, adst, N, K);

        gat_fused_kernel<<<(N + 3) / 4, 256, 0, stream>>>(bufA, asrc, adst, rowptr, csrsrc,
                                                          bl[layer], bufB, N);
    }

    pool_fc_kernel<<<G, 256, 0, stream>>>(bufB, batch, N, Wfc, bfc, out);
}

// Round 4
// 724.323 us; speedup vs baseline: 4.0289x; 1.1631x over previous
//
#include <hip/hip_runtime.h>
#include <hip/hip_bf16.h>

typedef short short8 __attribute__((ext_vector_type(8)));
typedef float floatx4 __attribute__((ext_vector_type(4)));
typedef unsigned short ushort_t;

__device__ __forceinline__ ushort_t f2bf(float v) {
    __hip_bfloat16 h = __float2bfloat16(v);
    return *(ushort_t*)&h;
}
__device__ __forceinline__ float bf2f(ushort_t u) {
    __hip_bfloat16 h = *(__hip_bfloat16*)&u;
    return __bfloat162float(h);
}

// ---------------- W pre-transpose + split: W[K][256] fp32 -> Bt{hi,lo}[256][K] bf16 ----------------
__global__ __launch_bounds__(256) void wsplit_kernel(const float* __restrict__ W,
                                                     ushort_t* __restrict__ Bthi,
                                                     ushort_t* __restrict__ Btlo, int K) {
    int idx = blockIdx.x * 256 + threadIdx.x;
    if (idx >= K * 256) return;
    int n = idx & 255, k = idx >> 8;
    float v = W[(size_t)k * 256 + n];
    ushort_t h = f2bf(v);
    float r = v - bf2f(h);
    Bthi[(size_t)n * K + k] = h;
    Btlo[(size_t)n * K + k] = f2bf(r);
}

// ---------------- MFMA split-bf16 GEMM: C[N,256] = A[N,K] @ W[K,256] (fp32-accurate) -------------
// 128x128 tile per block (4 waves, 64x64 per wave), BK=32, 16x16x32 bf16 MFMA, 3-term split.
// Epilogue: C store + fused alpha dot products (shuffle-reduce + global atomics).
#define ASTR 40
#define BSTR 56
__global__ __launch_bounds__(256, 2) void gemm_mfma(const float* __restrict__ A,
                                                    const ushort_t* __restrict__ Bthi,
                                                    const ushort_t* __restrict__ Btlo,
                                                    float* __restrict__ C,
                                                    const float* __restrict__ a_src,
                                                    const float* __restrict__ a_dst,
                                                    float* __restrict__ asrc_out,
                                                    float* __restrict__ adst_out,
                                                    int N, int K) {
    __shared__ ushort_t Ahi[128 * ASTR];
    __shared__ ushort_t Alo[128 * ASTR];
    __shared__ ushort_t Bhi[128 * BSTR];
    __shared__ ushort_t Blo[128 * BSTR];

    const int tid = threadIdx.x;
    const int wave = tid >> 6, lane = tid & 63;
    const int wr = wave & 1, wc = wave >> 1;     // wave row / col within 2x2
    const int q = lane >> 4, l15 = lane & 15;
    const int rowBase = blockIdx.x * 128;
    const int colBase = blockIdx.y * 128;

    floatx4 acc[4][4];
#pragma unroll
    for (int i = 0; i < 4; ++i)
#pragma unroll
        for (int j = 0; j < 4; ++j) acc[i][j] = (floatx4)0.f;

    const int a_row = tid >> 1;          // 0..127
    const int a_k0  = (tid & 1) * 16;    // 0 or 16
    const int b_n   = tid >> 1;          // 0..127
    const int b_k0  = (tid & 1) * 16;

    for (int kc = 0; kc < K; kc += 32) {
        // ---- stage A tile (fp32 -> hi/lo bf16) ----
        {
            int grow = rowBase + a_row;
            float v[16];
            if (grow < N) {
                const float* ap = A + (size_t)grow * K + kc + a_k0;
                float4 t0 = *(const float4*)(ap + 0);
                float4 t1 = *(const float4*)(ap + 4);
                float4 t2 = *(const float4*)(ap + 8);
                float4 t3 = *(const float4*)(ap + 12);
                v[0]=t0.x; v[1]=t0.y; v[2]=t0.z; v[3]=t0.w;
                v[4]=t1.x; v[5]=t1.y; v[6]=t1.z; v[7]=t1.w;
                v[8]=t2.x; v[9]=t2.y; v[10]=t2.z; v[11]=t2.w;
                v[12]=t3.x; v[13]=t3.y; v[14]=t3.z; v[15]=t3.w;
            } else {
#pragma unroll
                for (int i = 0; i < 16; ++i) v[i] = 0.f;
            }
            int base = a_row * ASTR + a_k0;
#pragma unroll
            for (int i = 0; i < 16; i += 2) {
                ushort_t h0 = f2bf(v[i]),     h1 = f2bf(v[i + 1]);
                ushort_t l0 = f2bf(v[i] - bf2f(h0));
                ushort_t l1 = f2bf(v[i + 1] - bf2f(h1));
                *(uint*)&Ahi[base + i] = (uint)h0 | ((uint)h1 << 16);
                *(uint*)&Alo[base + i] = (uint)l0 | ((uint)l1 << 16);
            }
        }
        // ---- stage B tile (already split bf16, k-contiguous) ----
        {
            const ushort_t* bh = Bthi + (size_t)(colBase + b_n) * K + kc + b_k0;
            const ushort_t* bl = Btlo + (size_t)(colBase + b_n) * K + kc + b_k0;
            int base = b_n * BSTR + b_k0;
            *(short8*)&Bhi[base + 0] = *(const short8*)(bh + 0);
            *(short8*)&Bhi[base + 8] = *(const short8*)(bh + 8);
            *(short8*)&Blo[base + 0] = *(const short8*)(bl + 0);
            *(short8*)&Blo[base + 8] = *(const short8*)(bl + 8);
        }
        __syncthreads();

        short8 afh[4], afl[4], bfh[4], bfl[4];
#pragma unroll
        for (int mt = 0; mt < 4; ++mt) {
            int r = wr * 64 + mt * 16 + l15;
            afh[mt] = *(short8*)&Ahi[r * ASTR + q * 8];
            afl[mt] = *(short8*)&Alo[r * ASTR + q * 8];
        }
#pragma unroll
        for (int nt = 0; nt < 4; ++nt) {
            int n = wc * 64 + nt * 16 + l15;
            bfh[nt] = *(short8*)&Bhi[n * BSTR + q * 8];
            bfl[nt] = *(short8*)&Blo[n * BSTR + q * 8];
        }
#pragma unroll
        for (int mt = 0; mt < 4; ++mt)
#pragma unroll
            for (int nt = 0; nt < 4; ++nt) {
                acc[mt][nt] = __builtin_amdgcn_mfma_f32_16x16x32_bf16(afh[mt], bfh[nt], acc[mt][nt], 0, 0, 0);
                acc[mt][nt] = __builtin_amdgcn_mfma_f32_16x16x32_bf16(afh[mt], bfl[nt], acc[mt][nt], 0, 0, 0);
                acc[mt][nt] = __builtin_amdgcn_mfma_f32_16x16x32_bf16(afl[mt], bfh[nt], acc[mt][nt], 0, 0, 0);
            }
        __syncthreads();
    }

    // ---- epilogue: C store + fused alpha ----
    float asv[4], adv[4];
#pragma unroll
    for (int nt = 0; nt < 4; ++nt) {
        int n = colBase + wc * 64 + nt * 16 + l15;
        asv[nt] = a_src[n];
        adv[nt] = a_dst[n];
    }
#pragma unroll
    for (int mt = 0; mt < 4; ++mt) {
#pragma unroll
        for (int reg = 0; reg < 4; ++reg) {
            int grow = rowBase + wr * 64 + mt * 16 + q * 4 + reg;
            float p1 = acc[mt][0][reg] * asv[0] + acc[mt][1][reg] * asv[1] +
                       acc[mt][2][reg] * asv[2] + acc[mt][3][reg] * asv[3];
            float p2 = acc[mt][0][reg] * adv[0] + acc[mt][1][reg] * adv[1] +
                       acc[mt][2][reg] * adv[2] + acc[mt][3][reg] * adv[3];
            if (grow < N) {
                float* crow = C + (size_t)grow * 256 + colBase + wc * 64 + l15;
#pragma unroll
                for (int nt = 0; nt < 4; ++nt) crow[nt * 16] = acc[mt][nt][reg];
            }
#pragma unroll
            for (int off = 1; off < 16; off <<= 1) {
                p1 += __shfl_xor(p1, off, 64);
                p2 += __shfl_xor(p2, off, 64);
            }
            if (l15 == 0 && grow < N) {
                atomicAdd(&asrc_out[grow], p1);
                atomicAdd(&adst_out[grow], p2);
            }
        }
    }
}

// ---------------- CSR build ----------------
__global__ __launch_bounds__(256) void count_kernel(const int* __restrict__ edst,
                                                    int* __restrict__ deg, int E) {
    int i = blockIdx.x * 256 + threadIdx.x;
    if (i < E) atomicAdd(&deg[edst[i]], 1);
}

__global__ __launch_bounds__(256) void scan1_kernel(const int* __restrict__ deg,
                                                    int* __restrict__ excl,
                                                    int* __restrict__ bsum, int N) {
    __shared__ int tmp[256];
    int tid = threadIdx.x;
    int i = blockIdx.x * 256 + tid;
    int v = (i < N) ? deg[i] : 0;
    tmp[tid] = v;
    __syncthreads();
    for (int off = 1; off < 256; off <<= 1) {
        int t = (tid >= off) ? tmp[tid - off] : 0;
        __syncthreads();
        tmp[tid] += t;
        __syncthreads();
    }
    if (i < N) excl[i] = tmp[tid] - v;
    if (tid == 255) bsum[blockIdx.x] = tmp[255];
}

__global__ __launch_bounds__(256) void scan2_kernel(int* __restrict__ bsum, int nb) {
    __shared__ int tmp[256];
    int tid = threadIdx.x;
    int v = (tid < nb) ? bsum[tid] : 0;
    tmp[tid] = v;
    __syncthreads();
    for (int off = 1; off < 256; off <<= 1) {
        int t = (tid >= off) ? tmp[tid - off] : 0;
        __syncthreads();
        tmp[tid] += t;
        __syncthreads();
    }
    if (tid < nb) bsum[tid] = tmp[tid] - v;
}

__global__ __launch_bounds__(256) void scan3_kernel(const int* __restrict__ excl,
                                                    const int* __restrict__ bsum,
                                                    int* __restrict__ rowptr,
                                                    int* __restrict__ cursor,
                                                    int N, int E) {
    int i = blockIdx.x * 256 + threadIdx.x;
    if (i < N) {
        int v = excl[i] + bsum[blockIdx.x];
        rowptr[i] = v;
        cursor[i] = v;
    }
    if (i == 0) rowptr[N] = E;
}

__global__ __launch_bounds__(256) void scatter_kernel(const int* __restrict__ esrc,
                                                      const int* __restrict__ edst,
                                                      int* __restrict__ cursor,
                                                      int* __restrict__ csr_src, int E) {
    int i = blockIdx.x * 256 + threadIdx.x;
    if (i < E) {
        int d = edst[i];
        int pos = atomicAdd(&cursor[d], 1);
        csr_src[pos] = esrc[i];
    }
}

// ---------------- fused GAT aggregation: one wave per dst node ----------------
__global__ __launch_bounds__(256) void gat_fused_kernel(const float* __restrict__ h,
                                                        const float* __restrict__ asrc,
                                                        const float* __restrict__ adst,
                                                        const int* __restrict__ rowptr,
                                                        const int* __restrict__ csr_src,
                                                        const float* __restrict__ bias,
                                                        float* __restrict__ out, int N) {
    int wave = threadIdx.x >> 6;
    int lane = threadIdx.x & 63;
    int d = blockIdx.x * 4 + wave;
    if (d >= N) return;

    float ad = adst[d];
    float es = asrc[d] + ad;
    es = es >= 0.f ? es : 0.2f * es;
    float m = es;
    float s = 1.0f;
    float4 acc = *(const float4*)(h + (size_t)d * 256 + lane * 4);

    int beg = rowptr[d], end = rowptr[d + 1];
    for (int base = beg; base < end; base += 64) {
        int cnt = min(64, end - base);
        int srci = 0;
        float e = -1e30f;
        if (lane < cnt) {
            srci = csr_src[base + lane];
            float v = asrc[srci] + ad;
            e = v >= 0.f ? v : 0.2f * v;
        }
        float cm = e;
#pragma unroll
        for (int off = 32; off > 0; off >>= 1) cm = fmaxf(cm, __shfl_xor(cm, off, 64));
        float mnew = fmaxf(m, cm);
        float scale = __expf(m - mnew);
        s *= scale;
        acc.x *= scale; acc.y *= scale; acc.z *= scale; acc.w *= scale;
        m = mnew;

        int j = 0;
        for (; j + 4 <= cnt; j += 4) {
            float e0 = __shfl(e, j, 64),     e1 = __shfl(e, j + 1, 64);
            float e2 = __shfl(e, j + 2, 64), e3 = __shfl(e, j + 3, 64);
            int s0 = __shfl(srci, j, 64),     s1i = __shfl(srci, j + 1, 64);
            int s2i = __shfl(srci, j + 2, 64), s3i = __shfl(srci, j + 3, 64);
            float4 hv0 = *(const float4*)(h + (size_t)s0 * 256 + lane * 4);
            float4 hv1 = *(const float4*)(h + (size_t)s1i * 256 + lane * 4);
            float4 hv2 = *(const float4*)(h + (size_t)s2i * 256 + lane * 4);
            float4 hv3 = *(const float4*)(h + (size_t)s3i * 256 + lane * 4);
            float p0 = __expf(e0 - m), p1 = __expf(e1 - m);
            float p2 = __expf(e2 - m), p3 = __expf(e3 - m);
            s += p0 + p1 + p2 + p3;
            acc.x += p0 * hv0.x + p1 * hv1.x + p2 * hv2.x + p3 * hv3.x;
            acc.y += p0 * hv0.y + p1 * hv1.y + p2 * hv2.y + p3 * hv3.y;
            acc.z += p0 * hv0.z + p1 * hv1.z + p2 * hv2.z + p3 * hv3.z;
            acc.w += p0 * hv0.w + p1 * hv1.w + p2 * hv2.w + p3 * hv3.w;
        }
        for (; j < cnt; ++j) {
            float ej = __shfl(e, j, 64);
            int sj = __shfl(srci, j, 64);
            float p = __expf(ej - m);
            float4 hv = *(const float4*)(h + (size_t)sj * 256 + lane * 4);
            s += p;
            acc.x += p * hv.x; acc.y += p * hv.y; acc.z += p * hv.z; acc.w += p * hv.w;
        }
    }
    float inv = 1.0f / s;
    float4 bv = *(const float4*)(bias + lane * 4);
    float4 o;
    o.x = fmaxf(acc.x * inv + bv.x, 0.f);
    o.y = fmaxf(acc.y * inv + bv.y, 0.f);
    o.z = fmaxf(acc.z * inv + bv.z, 0.f);
    o.w = fmaxf(acc.w * inv + bv.w, 0.f);
    *(float4*)(out + (size_t)d * 256 + lane * 4) = o;
}

// ---------------- fused mean pool + FC + softmax (batch is sorted) ----------------
__device__ __forceinline__ int lower_bound_i(const int* __restrict__ a, int n, int v) {
    int lo = 0, hi = n;
    while (lo < hi) {
        int mid = (lo + hi) >> 1;
        if (a[mid] < v) lo = mid + 1; else hi = mid;
    }
    return lo;
}

__global__ __launch_bounds__(256) void pool_fc_kernel(const float* __restrict__ h,
                                                      const int* __restrict__ batch,
                                                      int N,
                                                      const float* __restrict__ Wfc,
                                                      const float* __restrict__ bfc,
                                                      float* __restrict__ out) {
    __shared__ float red0[256];
    __shared__ float red1[256];
    int g = blockIdx.x;
    int c = threadIdx.x;
    int beg = lower_bound_i(batch, N, g);
    int end = lower_bound_i(batch, N, g + 1);
    float sum = 0.f;
    for (int n = beg; n < end; ++n) sum += h[(size_t)n * 256 + c];
    float cnt = (float)(end - beg);
    float v = sum / fmaxf(cnt, 1.0f);
    red0[c] = v * Wfc[c * 2 + 0];
    red1[c] = v * Wfc[c * 2 + 1];
    __syncthreads();
    for (int off = 128; off > 0; off >>= 1) {
        if (c < off) {
            red0[c] += red0[c + off];
            red1[c] += red1[c + off];
        }
        __syncthreads();
    }
    if (c == 0) {
        float l0 = red0[0] + bfc[0];
        float l1 = red1[0] + bfc[1];
        float mx = fmaxf(l0, l1);
        float e0 = expf(l0 - mx), e1 = expf(l1 - mx);
        float s = e0 + e1;
        out[g * 2 + 0] = e0 / s;
        out[g * 2 + 1] = e1 / s;
    }
}

// ---------------- launch ----------------
extern "C" void kernel_launch(void* const* d_in, const int* in_sizes, int n_in,
                              void* d_out, int out_size, void* d_ws, size_t ws_size,
                              hipStream_t stream) {
    const float* x    = (const float*)d_in[0];
    const int*   eidx = (const int*)d_in[1];
    const int*   batch= (const int*)d_in[2];
    const float* Wl[3]  = {(const float*)d_in[3], (const float*)d_in[7],  (const float*)d_in[11]};
    const float* asl[3] = {(const float*)d_in[4], (const float*)d_in[8],  (const float*)d_in[12]};
    const float* adl[3] = {(const float*)d_in[5], (const float*)d_in[9],  (const float*)d_in[13]};
    const float* bl[3]  = {(const float*)d_in[6], (const float*)d_in[10], (const float*)d_in[14]};
    const float* Wfc = (const float*)d_in[15];
    const float* bfc = (const float*)d_in[16];
    float* out = (float*)d_out;

    const int N  = in_sizes[2];
    const int E  = in_sizes[1] / 2;
    const int DH = 256;
    const int G  = 512;
    const int* esrc = eidx;
    const int* edst = eidx + E;

    char* ws = (char*)d_ws;
    size_t off = 0;
    const size_t featBytes = (size_t)N * DH * sizeof(float);
    float*    bufA   = (float*)(ws + off); off += featBytes;   // h (transformed)
    float*    bufB   = (float*)(ws + off); off += featBytes;   // layer output
    float*    asrc   = (float*)(ws + off); off += (size_t)N * sizeof(float);
    float*    adst   = (float*)(ws + off); off += (size_t)N * sizeof(float);
    int*      deg    = (int*)(ws + off);   off += (size_t)N * sizeof(int);
    int*      excl   = (int*)(ws + off);   off += (size_t)N * sizeof(int);
    int*      rowptr = (int*)(ws + off);   off += (size_t)(N + 1) * sizeof(int);
    int*      cursor = (int*)(ws + off);   off += (size_t)N * sizeof(int);
    int*      bsum   = (int*)(ws + off);   off += 1024;
    int*      csrsrc = (int*)(ws + off);   off += (size_t)E * sizeof(int);
    ushort_t* Bthi   = (ushort_t*)(ws + off); off += (size_t)256 * 256 * sizeof(ushort_t);
    ushort_t* Btlo   = (ushort_t*)(ws + off); off += (size_t)256 * 256 * sizeof(ushort_t);

    const int nbN = (N + 255) / 256;

    // ---- build CSR by dst (graph fixed across layers) ----
    hipMemsetAsync(deg, 0, (size_t)N * sizeof(int), stream);
    count_kernel<<<(E + 255) / 256, 256, 0, stream>>>(edst, deg, E);
    scan1_kernel<<<nbN, 256, 0, stream>>>(deg, excl, bsum, N);
    scan2_kernel<<<1, 256, 0, stream>>>(bsum, nbN);
    scan3_kernel<<<nbN, 256, 0, stream>>>(excl, bsum, rowptr, cursor, N, E);
    scatter_kernel<<<(E + 255) / 256, 256, 0, stream>>>(esrc, edst, cursor, csrsrc, E);

    for (int layer = 0; layer < 3; ++layer) {
        const float* in = (layer == 0) ? x : bufB;
        const int K = (layer == 0) ? 128 : 256;

        hipMemsetAsync(asrc, 0, 2 * (size_t)N * sizeof(float), stream);
        wsplit_kernel<<<K, 256, 0, stream>>>(Wl[layer], Bthi, Btlo, K);

        dim3 ggrid((N + 127) / 128, 2);
        gemm_mfma<<<ggrid, 256, 0, stream>>>(in, Bthi, Btlo, bufA,
                                             asl[layer], adl[layer], asrc, adst, N, K);

        gat_fused_kernel<<<(N + 3) / 4, 256, 0, stream>>>(bufA, asrc, adst, rowptr, csrsrc,
                                                          bl[layer], bufB, N);
    }

    pool_fc_kernel<<<G, 256, 0, stream>>>(bufB, batch, N, Wfc, bfc, out);
}

// Round 5
// 534.515 us; speedup vs baseline: 5.4595x; 1.3551x over previous
//
#include <hip/hip_runtime.h>
#include <hip/hip_bf16.h>

typedef short short8 __attribute__((ext_vector_type(8)));
typedef float floatx4 __attribute__((ext_vector_type(4)));
typedef unsigned short ushort_t;
typedef unsigned short ushort4v __attribute__((ext_vector_type(4)));

__device__ __forceinline__ ushort_t f2bf(float v) {
    __hip_bfloat16 h = __float2bfloat16(v);
    return *(ushort_t*)&h;
}
__device__ __forceinline__ float bf2f(ushort_t u) {
    return __uint_as_float(((unsigned)u) << 16);
}
__device__ __forceinline__ float4 ldh4(const ushort_t* p) {
    ushort4v u = *(const ushort4v*)p;
    return make_float4(bf2f(u.x), bf2f(u.y), bf2f(u.z), bf2f(u.w));
}

// ---------------- W pre-transpose + split: W[K][256] fp32 -> Bt{hi,lo}[256][K] bf16 ----------------
__global__ __launch_bounds__(256) void wsplit_kernel(const float* __restrict__ W,
                                                     ushort_t* __restrict__ Bthi,
                                                     ushort_t* __restrict__ Btlo, int K) {
    int idx = blockIdx.x * 256 + threadIdx.x;
    if (idx >= K * 256) return;
    int n = idx & 255, k = idx >> 8;
    float v = W[(size_t)k * 256 + n];
    ushort_t h = f2bf(v);
    float r = v - bf2f(h);
    Bthi[(size_t)n * K + k] = h;
    Btlo[(size_t)n * K + k] = f2bf(r);
}

// ---------------- MFMA split-bf16 GEMM: H[N,256](bf16) = A[N,K] @ W[K,256] ----------------------
// 128x128 tile per block (4 waves, 64x64 per wave), BK=32, 16x16x32 bf16 MFMA, 3-term split.
// fp32 accumulate; epilogue: bf16 H store + fused alpha dot products (fp32, shuffle + atomics).
#define ASTR 40
#define BSTR 56
__global__ __launch_bounds__(256, 2) void gemm_mfma(const float* __restrict__ A,
                                                    const ushort_t* __restrict__ Bthi,
                                                    const ushort_t* __restrict__ Btlo,
                                                    ushort_t* __restrict__ Hb,
                                                    const float* __restrict__ a_src,
                                                    const float* __restrict__ a_dst,
                                                    float* __restrict__ asrc_out,
                                                    float* __restrict__ adst_out,
                                                    int N, int K) {
    __shared__ ushort_t Ahi[128 * ASTR];
    __shared__ ushort_t Alo[128 * ASTR];
    __shared__ ushort_t Bhi[128 * BSTR];
    __shared__ ushort_t Blo[128 * BSTR];

    const int tid = threadIdx.x;
    const int wave = tid >> 6, lane = tid & 63;
    const int wr = wave & 1, wc = wave >> 1;     // wave row / col within 2x2
    const int q = lane >> 4, l15 = lane & 15;
    const int rowBase = blockIdx.x * 128;
    const int colBase = blockIdx.y * 128;

    floatx4 acc[4][4];
#pragma unroll
    for (int i = 0; i < 4; ++i)
#pragma unroll
        for (int j = 0; j < 4; ++j) acc[i][j] = (floatx4)0.f;

    const int a_row = tid >> 1;          // 0..127
    const int a_k0  = (tid & 1) * 16;    // 0 or 16
    const int b_n   = tid >> 1;          // 0..127
    const int b_k0  = (tid & 1) * 16;

    for (int kc = 0; kc < K; kc += 32) {
        // ---- stage A tile (fp32 -> hi/lo bf16) ----
        {
            int grow = rowBase + a_row;
            float v[16];
            if (grow < N) {
                const float* ap = A + (size_t)grow * K + kc + a_k0;
                float4 t0 = *(const float4*)(ap + 0);
                float4 t1 = *(const float4*)(ap + 4);
                float4 t2 = *(const float4*)(ap + 8);
                float4 t3 = *(const float4*)(ap + 12);
                v[0]=t0.x; v[1]=t0.y; v[2]=t0.z; v[3]=t0.w;
                v[4]=t1.x; v[5]=t1.y; v[6]=t1.z; v[7]=t1.w;
                v[8]=t2.x; v[9]=t2.y; v[10]=t2.z; v[11]=t2.w;
                v[12]=t3.x; v[13]=t3.y; v[14]=t3.z; v[15]=t3.w;
            } else {
#pragma unroll
                for (int i = 0; i < 16; ++i) v[i] = 0.f;
            }
            int base = a_row * ASTR + a_k0;
#pragma unroll
            for (int i = 0; i < 16; i += 2) {
                ushort_t h0 = f2bf(v[i]),     h1 = f2bf(v[i + 1]);
                ushort_t l0 = f2bf(v[i] - bf2f(h0));
                ushort_t l1 = f2bf(v[i + 1] - bf2f(h1));
                *(uint*)&Ahi[base + i] = (uint)h0 | ((uint)h1 << 16);
                *(uint*)&Alo[base + i] = (uint)l0 | ((uint)l1 << 16);
            }
        }
        // ---- stage B tile (already split bf16, k-contiguous) ----
        {
            const ushort_t* bh = Bthi + (size_t)(colBase + b_n) * K + kc + b_k0;
            const ushort_t* bl = Btlo + (size_t)(colBase + b_n) * K + kc + b_k0;
            int base = b_n * BSTR + b_k0;
            *(short8*)&Bhi[base + 0] = *(const short8*)(bh + 0);
            *(short8*)&Bhi[base + 8] = *(const short8*)(bh + 8);
            *(short8*)&Blo[base + 0] = *(const short8*)(bl + 0);
            *(short8*)&Blo[base + 8] = *(const short8*)(bl + 8);
        }
        __syncthreads();

        short8 afh[4], afl[4], bfh[4], bfl[4];
#pragma unroll
        for (int mt = 0; mt < 4; ++mt) {
            int r = wr * 64 + mt * 16 + l15;
            afh[mt] = *(short8*)&Ahi[r * ASTR + q * 8];
            afl[mt] = *(short8*)&Alo[r * ASTR + q * 8];
        }
#pragma unroll
        for (int nt = 0; nt < 4; ++nt) {
            int n = wc * 64 + nt * 16 + l15;
            bfh[nt] = *(short8*)&Bhi[n * BSTR + q * 8];
            bfl[nt] = *(short8*)&Blo[n * BSTR + q * 8];
        }
#pragma unroll
        for (int mt = 0; mt < 4; ++mt)
#pragma unroll
            for (int nt = 0; nt < 4; ++nt) {
                acc[mt][nt] = __builtin_amdgcn_mfma_f32_16x16x32_bf16(afh[mt], bfh[nt], acc[mt][nt], 0, 0, 0);
                acc[mt][nt] = __builtin_amdgcn_mfma_f32_16x16x32_bf16(afh[mt], bfl[nt], acc[mt][nt], 0, 0, 0);
                acc[mt][nt] = __builtin_amdgcn_mfma_f32_16x16x32_bf16(afl[mt], bfh[nt], acc[mt][nt], 0, 0, 0);
            }
        __syncthreads();
    }

    // ---- epilogue: bf16 H store + fused alpha (fp32) ----
    float asv[4], adv[4];
#pragma unroll
    for (int nt = 0; nt < 4; ++nt) {
        int n = colBase + wc * 64 + nt * 16 + l15;
        asv[nt] = a_src[n];
        adv[nt] = a_dst[n];
    }
#pragma unroll
    for (int mt = 0; mt < 4; ++mt) {
#pragma unroll
        for (int reg = 0; reg < 4; ++reg) {
            int grow = rowBase + wr * 64 + mt * 16 + q * 4 + reg;
            float p1 = acc[mt][0][reg] * asv[0] + acc[mt][1][reg] * asv[1] +
                       acc[mt][2][reg] * asv[2] + acc[mt][3][reg] * asv[3];
            float p2 = acc[mt][0][reg] * adv[0] + acc[mt][1][reg] * adv[1] +
                       acc[mt][2][reg] * adv[2] + acc[mt][3][reg] * adv[3];
            if (grow < N) {
                ushort_t* crow = Hb + (size_t)grow * 256 + colBase + wc * 64 + l15;
#pragma unroll
                for (int nt = 0; nt < 4; ++nt) crow[nt * 16] = f2bf(acc[mt][nt][reg]);
            }
#pragma unroll
            for (int off = 1; off < 16; off <<= 1) {
                p1 += __shfl_xor(p1, off, 64);
                p2 += __shfl_xor(p2, off, 64);
            }
            if (l15 == 0 && grow < N) {
                atomicAdd(&asrc_out[grow], p1);
                atomicAdd(&adst_out[grow], p2);
            }
        }
    }
}

// ---------------- CSR build ----------------
__global__ __launch_bounds__(256) void count_kernel(const int* __restrict__ edst,
                                                    int* __restrict__ deg, int E) {
    int i = blockIdx.x * 256 + threadIdx.x;
    if (i < E) atomicAdd(&deg[edst[i]], 1);
}

__global__ __launch_bounds__(256) void scan1_kernel(const int* __restrict__ deg,
                                                    int* __restrict__ excl,
                                                    int* __restrict__ bsum, int N) {
    __shared__ int tmp[256];
    int tid = threadIdx.x;
    int i = blockIdx.x * 256 + tid;
    int v = (i < N) ? deg[i] : 0;
    tmp[tid] = v;
    __syncthreads();
    for (int off = 1; off < 256; off <<= 1) {
        int t = (tid >= off) ? tmp[tid - off] : 0;
        __syncthreads();
        tmp[tid] += t;
        __syncthreads();
    }
    if (i < N) excl[i] = tmp[tid] - v;
    if (tid == 255) bsum[blockIdx.x] = tmp[255];
}

__global__ __launch_bounds__(256) void scan2_kernel(int* __restrict__ bsum, int nb) {
    __shared__ int tmp[256];
    int tid = threadIdx.x;
    int v = (tid < nb) ? bsum[tid] : 0;
    tmp[tid] = v;
    __syncthreads();
    for (int off = 1; off < 256; off <<= 1) {
        int t = (tid >= off) ? tmp[tid - off] : 0;
        __syncthreads();
        tmp[tid] += t;
        __syncthreads();
    }
    if (tid < nb) bsum[tid] = tmp[tid] - v;
}

__global__ __launch_bounds__(256) void scan3_kernel(const int* __restrict__ excl,
                                                    const int* __restrict__ bsum,
                                                    int* __restrict__ rowptr,
                                                    int* __restrict__ cursor,
                                                    int N, int E) {
    int i = blockIdx.x * 256 + threadIdx.x;
    if (i < N) {
        int v = excl[i] + bsum[blockIdx.x];
        rowptr[i] = v;
        cursor[i] = v;
    }
    if (i == 0) rowptr[N] = E;
}

__global__ __launch_bounds__(256) void scatter_kernel(const int* __restrict__ esrc,
                                                      const int* __restrict__ edst,
                                                      int* __restrict__ cursor,
                                                      int* __restrict__ csr_src, int E) {
    int i = blockIdx.x * 256 + threadIdx.x;
    if (i < E) {
        int d = edst[i];
        int pos = atomicAdd(&cursor[d], 1);
        csr_src[pos] = esrc[i];
    }
}

// ---------------- fused GAT aggregation: one wave per dst node (bf16 h gather) ----------------
__global__ __launch_bounds__(256) void gat_fused_kernel(const ushort_t* __restrict__ hb,
                                                        const float* __restrict__ asrc,
                                                        const float* __restrict__ adst,
                                                        const int* __restrict__ rowptr,
                                                        const int* __restrict__ csr_src,
                                                        const float* __restrict__ bias,
                                                        float* __restrict__ out, int N) {
    int wave = threadIdx.x >> 6;
    int lane = threadIdx.x & 63;
    int d = blockIdx.x * 4 + wave;
    if (d >= N) return;

    float ad = adst[d];
    float es = asrc[d] + ad;
    es = es >= 0.f ? es : 0.2f * es;
    float m = es;
    float s = 1.0f;
    float4 acc = ldh4(hb + (size_t)d * 256 + lane * 4);

    int beg = rowptr[d], end = rowptr[d + 1];
    for (int base = beg; base < end; base += 64) {
        int cnt = min(64, end - base);
        int srci = 0;
        float e = -1e30f;
        if (lane < cnt) {
            srci = csr_src[base + lane];
            float v = asrc[srci] + ad;
            e = v >= 0.f ? v : 0.2f * v;
        }
        float cm = e;
#pragma unroll
        for (int off = 32; off > 0; off >>= 1) cm = fmaxf(cm, __shfl_xor(cm, off, 64));
        float mnew = fmaxf(m, cm);
        float scale = __expf(m - mnew);
        s *= scale;
        acc.x *= scale; acc.y *= scale; acc.z *= scale; acc.w *= scale;
        m = mnew;

        int j = 0;
        for (; j + 4 <= cnt; j += 4) {
            float e0 = __shfl(e, j, 64),     e1 = __shfl(e, j + 1, 64);
            float e2 = __shfl(e, j + 2, 64), e3 = __shfl(e, j + 3, 64);
            int s0 = __shfl(srci, j, 64),     s1i = __shfl(srci, j + 1, 64);
            int s2i = __shfl(srci, j + 2, 64), s3i = __shfl(srci, j + 3, 64);
            float4 hv0 = ldh4(hb + (size_t)s0 * 256 + lane * 4);
            float4 hv1 = ldh4(hb + (size_t)s1i * 256 + lane * 4);
            float4 hv2 = ldh4(hb + (size_t)s2i * 256 + lane * 4);
            float4 hv3 = ldh4(hb + (size_t)s3i * 256 + lane * 4);
            float p0 = __expf(e0 - m), p1 = __expf(e1 - m);
            float p2 = __expf(e2 - m), p3 = __expf(e3 - m);
            s += p0 + p1 + p2 + p3;
            acc.x += p0 * hv0.x + p1 * hv1.x + p2 * hv2.x + p3 * hv3.x;
            acc.y += p0 * hv0.y + p1 * hv1.y + p2 * hv2.y + p3 * hv3.y;
            acc.z += p0 * hv0.z + p1 * hv1.z + p2 * hv2.z + p3 * hv3.z;
            acc.w += p0 * hv0.w + p1 * hv1.w + p2 * hv2.w + p3 * hv3.w;
        }
        for (; j < cnt; ++j) {
            float ej = __shfl(e, j, 64);
            int sj = __shfl(srci, j, 64);
            float p = __expf(ej - m);
            float4 hv = ldh4(hb + (size_t)sj * 256 + lane * 4);
            s += p;
            acc.x += p * hv.x; acc.y += p * hv.y; acc.z += p * hv.z; acc.w += p * hv.w;
        }
    }
    float inv = 1.0f / s;
    float4 bv = *(const float4*)(bias + lane * 4);
    float4 o;
    o.x = fmaxf(acc.x * inv + bv.x, 0.f);
    o.y = fmaxf(acc.y * inv + bv.y, 0.f);
    o.z = fmaxf(acc.z * inv + bv.z, 0.f);
    o.w = fmaxf(acc.w * inv + bv.w, 0.f);
    *(float4*)(out + (size_t)d * 256 + lane * 4) = o;
}

// ---------------- fused mean pool + FC + softmax (batch is sorted) ----------------
__device__ __forceinline__ int lower_bound_i(const int* __restrict__ a, int n, int v) {
    int lo = 0, hi = n;
    while (lo < hi) {
        int mid = (lo + hi) >> 1;
        if (a[mid] < v) lo = mid + 1; else hi = mid;
    }
    return lo;
}

__global__ __launch_bounds__(256) void pool_fc_kernel(const float* __restrict__ h,
                                                      const int* __restrict__ batch,
                                                      int N,
                                                      const float* __restrict__ Wfc,
                                                      const float* __restrict__ bfc,
                                                      float* __restrict__ out) {
    __shared__ float red0[256];
    __shared__ float red1[256];
    int g = blockIdx.x;
    int c = threadIdx.x;
    int beg = lower_bound_i(batch, N, g);
    int end = lower_bound_i(batch, N, g + 1);
    float sum = 0.f;
    for (int n = beg; n < end; ++n) sum += h[(size_t)n * 256 + c];
    float cnt = (float)(end - beg);
    float v = sum / fmaxf(cnt, 1.0f);
    red0[c] = v * Wfc[c * 2 + 0];
    red1[c] = v * Wfc[c * 2 + 1];
    __syncthreads();
    for (int off = 128; off > 0; off >>= 1) {
        if (c < off) {
            red0[c] += red0[c + off];
            red1[c] += red1[c + off];
        }
        __syncthreads();
    }
    if (c == 0) {
        float l0 = red0[0] + bfc[0];
        float l1 = red1[0] + bfc[1];
        float mx = fmaxf(l0, l1);
        float e0 = expf(l0 - mx), e1 = expf(l1 - mx);
        float s = e0 + e1;
        out[g * 2 + 0] = e0 / s;
        out[g * 2 + 1] = e1 / s;
    }
}

// ---------------- launch ----------------
extern "C" void kernel_launch(void* const* d_in, const int* in_sizes, int n_in,
                              void* d_out, int out_size, void* d_ws, size_t ws_size,
                              hipStream_t stream) {
    const float* x    = (const float*)d_in[0];
    const int*   eidx = (const int*)d_in[1];
    const int*   batch= (const int*)d_in[2];
    const float* Wl[3]  = {(const float*)d_in[3], (const float*)d_in[7],  (const float*)d_in[11]};
    const float* asl[3] = {(const float*)d_in[4], (const float*)d_in[8],  (const float*)d_in[12]};
    const float* adl[3] = {(const float*)d_in[5], (const float*)d_in[9],  (const float*)d_in[13]};
    const float* bl[3]  = {(const float*)d_in[6], (const float*)d_in[10], (const float*)d_in[14]};
    const float* Wfc = (const float*)d_in[15];
    const float* bfc = (const float*)d_in[16];
    float* out = (float*)d_out;

    const int N  = in_sizes[2];
    const int E  = in_sizes[1] / 2;
    const int DH = 256;
    const int G  = 512;
    const int* esrc = eidx;
    const int* edst = eidx + E;

    char* ws = (char*)d_ws;
    size_t off = 0;
    const size_t featBytes = (size_t)N * DH * sizeof(float);
    ushort_t* hb     = (ushort_t*)(ws + off); off += (size_t)N * DH * sizeof(ushort_t); // h bf16
    float*    bufB   = (float*)(ws + off); off += featBytes;   // layer output (fp32)
    float*    asrc   = (float*)(ws + off); off += (size_t)N * sizeof(float);
    float*    adst   = (float*)(ws + off); off += (size_t)N * sizeof(float);
    int*      deg    = (int*)(ws + off);   off += (size_t)N * sizeof(int);
    int*      excl   = (int*)(ws + off);   off += (size_t)N * sizeof(int);
    int*      rowptr = (int*)(ws + off);   off += (size_t)(N + 1) * sizeof(int);
    int*      cursor = (int*)(ws + off);   off += (size_t)N * sizeof(int);
    int*      bsum   = (int*)(ws + off);   off += 1024;
    int*      csrsrc = (int*)(ws + off);   off += (size_t)E * sizeof(int);
    ushort_t* Bthi   = (ushort_t*)(ws + off); off += (size_t)256 * 256 * sizeof(ushort_t);
    ushort_t* Btlo   = (ushort_t*)(ws + off); off += (size_t)256 * 256 * sizeof(ushort_t);

    const int nbN = (N + 255) / 256;

    // ---- build CSR by dst (graph fixed across layers) ----
    hipMemsetAsync(deg, 0, (size_t)N * sizeof(int), stream);
    count_kernel<<<(E + 255) / 256, 256, 0, stream>>>(edst, deg, E);
    scan1_kernel<<<nbN, 256, 0, stream>>>(deg, excl, bsum, N);
    scan2_kernel<<<1, 256, 0, stream>>>(bsum, nbN);
    scan3_kernel<<<nbN, 256, 0, stream>>>(excl, bsum, rowptr, cursor, N, E);
    scatter_kernel<<<(E + 255) / 256, 256, 0, stream>>>(esrc, edst, cursor, csrsrc, E);

    for (int layer = 0; layer < 3; ++layer) {
        const float* in = (layer == 0) ? x : bufB;
        const int K = (layer == 0) ? 128 : 256;

        hipMemsetAsync(asrc, 0, 2 * (size_t)N * sizeof(float), stream);
        wsplit_kernel<<<K, 256, 0, stream>>>(Wl[layer], Bthi, Btlo, K);

        dim3 ggrid((N + 127) / 128, 2);
        gemm_mfma<<<ggrid, 256, 0, stream>>>(in, Bthi, Btlo, hb,
                                             asl[layer], adl[layer], asrc, adst, N, K);

        gat_fused_kernel<<<(N + 3) / 4, 256, 0, stream>>>(hb, asrc, adst, rowptr, csrsrc,
                                                          bl[layer], bufB, N);
    }

    pool_fc_kernel<<<G, 256, 0, stream>>>(bufB, batch, N, Wfc, bfc, out);
}